// Round 13
// baseline (268.748 us; speedup 1.0000x reference)
//
#include <hip/hip_runtime.h>
#include <hip/hip_bf16.h>

// GroupLinearEncoder: N=64, L0=257,C0=1024, L1=197,C1=768, H=1024, P=2048, G=8, K=39548
// v14:
//   prep: cvt/pad/zero + LDS-tiled w1 transpose (unchanged from v12)
//   gemm_fused_dual: m97 geometry — 128x128 tile, BK=64, 4 waves, SINGLE 32KB LDS
//     buffer, plain 2-syncthreads loop (32 MFMA/wave-step); LDS-staged z epilogue.
//   bn_latent; s_combine (unchanged)
//   gemm_embed: v12 version (BK=64 As+Bs dbuf, counted vmcnt(6), direct out)

typedef __attribute__((ext_vector_type(4))) float f32x4;
typedef __attribute__((ext_vector_type(8))) short bf16x8;

__device__ __forceinline__ short f2bf(float v) {
  __hip_bfloat16 h = __float2bfloat16(v);
  union { __hip_bfloat16 b; short s; } u; u.b = h; return u.s;
}

__device__ __forceinline__ void gload16(const short* g, short* l) {
  __builtin_amdgcn_global_load_lds(
      (const __attribute__((address_space(1))) void*)g,
      (__attribute__((address_space(3))) void*)l, 16, 0, 0);
}

__device__ __forceinline__ void gload16f(const float* g, float* l) {
  __builtin_amdgcn_global_load_lds(
      (const __attribute__((address_space(1))) void*)g,
      (__attribute__((address_space(3))) void*)l, 16, 0, 0);
}

__device__ __forceinline__ void cvt8(const float* __restrict__ in,
                                     short* __restrict__ out, size_t i) {
  const float4* p = reinterpret_cast<const float4*>(in) + 2 * i;
  float4 a = p[0], b = p[1];
  bf16x8 o;
  o[0] = f2bf(a.x); o[1] = f2bf(a.y); o[2] = f2bf(a.z); o[3] = f2bf(a.w);
  o[4] = f2bf(b.x); o[5] = f2bf(b.y); o[6] = f2bf(b.z); o[7] = f2bf(b.w);
  *reinterpret_cast<bf16x8*>(out + 8 * i) = o;
}

// blocks [0,13968): elementwise cvt/pad/zero; [13968,14480): tiled w1 transpose.
__global__ __launch_bounds__(256) void prep(
    const float* __restrict__ x0, const float* __restrict__ x1,
    const float* __restrict__ w20, const float* __restrict__ w21,
    const float* __restrict__ w10, const float* __restrict__ w11,
    short* __restrict__ x0b, short* __restrict__ x1b,
    short* __restrict__ w20b, short* __restrict__ w21b,
    float* __restrict__ w1t0, float* __restrict__ w1t1,
    float* __restrict__ zz)
{
  __shared__ float tile[32][33];
  if (blockIdx.x >= 13968) {
    int b = blockIdx.x - 13968;
    const float* src; float* dst; int Lw;
    if (b < 288) { src = w10; dst = w1t0; Lw = 257; }
    else         { b -= 288; src = w11; dst = w1t1; Lw = 197; }
    int kt = b & 31, lt = b >> 5;
    int c = threadIdx.x & 31, r8 = threadIdx.x >> 5;
#pragma unroll
    for (int i = 0; i < 4; ++i) {
      int a = r8 + 8 * i;
      int l = lt * 32 + c;
      tile[a][c] = (l < Lw) ? src[(size_t)(kt * 32 + a) * Lw + l] : 0.f;
    }
    __syncthreads();
#pragma unroll
    for (int i = 0; i < 4; ++i) {
      int bl = r8 + 8 * i;
      int l = lt * 32 + bl;
      if (l < Lw) dst[(size_t)l * 1024 + kt * 32 + c] = tile[c][bl];
    }
    return;
  }
  size_t i = (size_t)blockIdx.x * 256 + threadIdx.x;
  const size_t C0 = 2105344;            // x0 cvt  (16448*1024/8)
  const size_t C1 = C0 + 8192;          // x0 pad
  const size_t C2 = C1 + 1210368;       // x1 cvt  (12608*768/8)
  const size_t C3 = C2 + 6144;          // x1 pad
  const size_t C4 = C3 + 131072;        // w2_0
  const size_t C5 = C4 + 98304;         // w2_1
  // C5 + 16384 (z zero) = 3575808 = 256*13968
  if (i < C0) { cvt8(x0, x0b, i); return; }
  if (i < C1) {
    bf16x8 zv = {};
    *reinterpret_cast<bf16x8*>(x0b + (size_t)16448 * 1024 + 8 * (i - C0)) = zv;
    return;
  }
  if (i < C2) { cvt8(x1, x1b, i - C1); return; }
  if (i < C3) {
    bf16x8 zv = {};
    *reinterpret_cast<bf16x8*>(x1b + (size_t)12608 * 768 + 8 * (i - C2)) = zv;
    return;
  }
  if (i < C4) { cvt8(w20, w20b, i - C3); return; }
  if (i < C5) { cvt8(w21, w21b, i - C4); return; }
  f32x4 z4 = {};
  f32x4* zp = reinterpret_cast<f32x4*>(zz) + 2 * (i - C5);
  zp[0] = z4; zp[1] = z4;
}

// ---- fused feature-projection GEMM body — m97 geometry ----
// 128x128 tile, BK=64, 4 waves (2x2, 64x64 each), single LDS buffer,
// __syncthreads; stage; __syncthreads; compute (32 MFMA/wave-step).
// Epilogue: z[n,col] += sum_l C[row,col]*w1t[l*1024+col] via 2-deep LDS zacc.
template<int L>
__device__ __forceinline__ void fused_body(
    const short* __restrict__ Ab, const short* __restrict__ Bb,
    const float* __restrict__ w1t, float* __restrict__ z,
    int M, int K, int orig, short* As, short* Bs, float* zacc, int tid)
{
  const int lane = tid & 63;
  const int wave = tid >> 6;             // 0..3
  const int wm = wave >> 1, wn = wave & 1;
  const int tile_m = (orig >> 3) * 128;  // Mpad multiple of 128 -> rows in-range
  const int tile_n = (orig & 7) * 128;
  const int rl = lane & 15;
  const int lh = lane >> 4;

  if (tid < 256) zacc[tid] = 0.f;        // 2 x 128 entries

  f32x4 acc[4][4] = {};
  const int nt = K >> 6;

  for (int t = 0; t < nt; ++t) {
    const int k0 = t * 64;
    __syncthreads();                     // all reads of previous tile done
    // A: 128 rows x 64 bf16 = 16KB, 128B rows = 8 chunks, swz cc^(r&7)
#pragma unroll
    for (int c = 0; c < 4; ++c) {
      int o = (c * 256 + tid) * 16;
      int r = o >> 7;
      int cc = ((o >> 4) & 7) ^ (r & 7);
      gload16(Ab + (size_t)(tile_m + r) * K + k0 + cc * 8, (short*)((char*)As + o));
    }
    // B: 128 rows x 64 bf16 = 16KB
#pragma unroll
    for (int c = 0; c < 4; ++c) {
      int o = (c * 256 + tid) * 16;
      int r = o >> 7;
      int cc = ((o >> 4) & 7) ^ (r & 7);
      gload16(Bb + (size_t)(tile_n + r) * K + k0 + cc * 8, (short*)((char*)Bs + o));
    }
    __syncthreads();                     // compiler drains vmcnt before barrier

#pragma unroll
    for (int ks = 0; ks < 2; ++ks) {
      bf16x8 af[4], bfr[4];
#pragma unroll
      for (int mi = 0; mi < 4; ++mi) {
        int r = wm * 64 + mi * 16 + rl;
        int j = (ks * 4 + lh) ^ (r & 7);
        af[mi] = *reinterpret_cast<const bf16x8*>((const char*)As + r * 128 + j * 16);
      }
#pragma unroll
      for (int ni = 0; ni < 4; ++ni) {
        int r = wn * 64 + ni * 16 + rl;
        int j = (ks * 4 + lh) ^ (r & 7);
        bfr[ni] = *reinterpret_cast<const bf16x8*>((const char*)Bs + r * 128 + j * 16);
      }
#pragma unroll
      for (int mi = 0; mi < 4; ++mi)
#pragma unroll
        for (int ni = 0; ni < 4; ++ni)
          acc[mi][ni] = __builtin_amdgcn_mfma_f32_16x16x32_bf16(af[mi], bfr[ni], acc[mi][ni], 0, 0, 0);
    }
  }

  // epilogue: per-thread partials -> LDS zacc[dn][colL] (dn in {0,1}), then one
  // global atomicAdd per entry. C/D: col=lane&15, row=(lane>>4)*4+j (m89).
  const int nbase = tile_m / L;
#pragma unroll
  for (int ni = 0; ni < 4; ++ni) {
    int colL = wn * 64 + ni * 16 + rl;   // 0..127
    int col = tile_n + colL;
    float zac = 0.f;
    int curdn = -1;
#pragma unroll
    for (int mi = 0; mi < 4; ++mi) {
#pragma unroll
      for (int j = 0; j < 4; ++j) {
        int row = tile_m + wm * 64 + mi * 16 + lh * 4 + j;
        if (row < M) {
          int n = row / L, l = row - n * L;
          float v = acc[mi][ni][j] * w1t[(size_t)l * 1024 + col];
          int dn = n - nbase;
          if (dn != curdn) {
            if (curdn >= 0) atomicAdd(&zacc[curdn * 128 + colL], zac);
            curdn = dn; zac = 0.f;
          }
          zac += v;
        }
      }
    }
    if (curdn >= 0) atomicAdd(&zacc[curdn * 128 + colL], zac);
  }
  __syncthreads();
  {
    int dn = tid >> 7, c = tid & 127;    // 256 threads cover 2x128
    int mtop = tile_m + 127; if (mtop > M - 1) mtop = M - 1;
    int nhi = mtop / L;
    int n = nbase + dn;
    if (n <= nhi)
      atomicAdd(z + (size_t)n * 1024 + tile_n + c, zacc[tid]);
  }
}

// blocks [0,1032) path0 (129x8 tiles), [1032,1824) path1 (99x8).
// Per-half XCD-chunked swizzle (1032%8==0, 792%8==0).
__global__ __launch_bounds__(256) void gemm_fused_dual(
    const short* __restrict__ x0b, const short* __restrict__ w20b,
    const float* __restrict__ w1t0, float* __restrict__ z0,
    const short* __restrict__ x1b, const short* __restrict__ w21b,
    const float* __restrict__ w1t1, float* __restrict__ z1)
{
  __shared__ short As[128 * 64];   // 16KB
  __shared__ short Bs[128 * 64];   // 16KB
  __shared__ float zacc[256];      // 1KB
  const int flat = blockIdx.x;
  const int tid = threadIdx.x;
  if (flat < 1032) {
    const int orig = (flat & 7) * 129 + (flat >> 3);
    fused_body<257>(x0b, w20b, w1t0, z0, 16448, 1024, orig, As, Bs, zacc, tid);
  } else {
    const int f = flat - 1032;
    const int orig = (f & 7) * 99 + (f >> 3);
    fused_body<197>(x1b, w21b, w1t1, z1, 12608, 768, orig, As, Bs, zacc, tid);
  }
}

// BN(z0), BN(z1) (biased stats over n=64), latent=0.5*(...+...), stored lat[n*1024+k]
__global__ void bn_latent(const float* __restrict__ z0, const float* __restrict__ z1,
                          const float* __restrict__ g0, const float* __restrict__ b0,
                          const float* __restrict__ g1, const float* __restrict__ b1,
                          float* __restrict__ lat)
{
  int k = blockIdx.x * blockDim.x + threadIdx.x;
  if (k >= 1024) return;
  float s0 = 0.f, q0 = 0.f, s1 = 0.f, q1 = 0.f;
  for (int n = 0; n < 64; ++n) {
    float v = z0[n * 1024 + k]; s0 += v; q0 += v * v;
    float w = z1[n * 1024 + k]; s1 += w; q1 += w * w;
  }
  float mu0 = s0 * (1.f / 64.f), var0 = q0 * (1.f / 64.f) - mu0 * mu0;
  float mu1 = s1 * (1.f / 64.f), var1 = q1 * (1.f / 64.f) - mu1 * mu1;
  float sc0 = g0[k] * rsqrtf(var0 + 1e-5f);
  float sc1 = g1[k] * rsqrtf(var1 + 1e-5f);
  float be0 = b0[k], be1 = b1[k];
  for (int n = 0; n < 64; ++n) {
    float v = sc0 * (z0[n * 1024 + k] - mu0) + be0
            + sc1 * (z1[n * 1024 + k] - mu1) + be1;
    lat[n * 1024 + k] = 0.5f * v;
  }
}

// sb[n,p] = bf16( lat[n,:]·(sw[p,:]+fw[g_n*2048+p,:]) + fb[g_n*2048+p] )
__global__ __launch_bounds__(512) void s_combine(
    const float* __restrict__ lat, const float* __restrict__ sw,
    const float* __restrict__ fw, const float* __restrict__ fb,
    const int* __restrict__ idx, short* __restrict__ sb)
{
  __shared__ int nlist[64];
  __shared__ int ncnt;
  const int g  = blockIdx.x >> 5;
  const int pc = blockIdx.x & 31;
  const int tid = threadIdx.x;
  const int lane = tid & 63;
  const int wave = tid >> 6;

  if (wave == 0) {
    int match = (idx[lane] == g) ? 1 : 0;
    unsigned long long m = __ballot(match);
    if (match) {
      int pos = __popcll(m & ((1ull << lane) - 1ull));
      nlist[pos] = lane;
    }
    if (lane == 0) ncnt = __popcll(m);
  }
  __syncthreads();
  const int cnt = ncnt;
  if (cnt == 0) return;

  for (int c0 = 0; c0 < cnt; c0 += 8) {
    const int nc = (cnt - c0 < 8) ? (cnt - c0) : 8;
    f32x4 latr[8][4];
#pragma unroll
    for (int j2 = 0; j2 < 8; ++j2)
      if (j2 < nc) {
        const f32x4* lp = reinterpret_cast<const f32x4*>(lat + (size_t)nlist[c0 + j2] * 1024);
#pragma unroll
        for (int q = 0; q < 4; ++q) latr[j2][q] = lp[q * 64 + lane];
      }
#pragma unroll 2
    for (int pi = 0; pi < 8; ++pi) {
      int p = pc * 64 + wave * 8 + pi;
      const f32x4* fp = reinterpret_cast<const f32x4*>(fw + ((size_t)g * 2048 + p) * 1024);
      const f32x4* sp = reinterpret_cast<const f32x4*>(sw + (size_t)p * 1024);
      f32x4 row[4];
#pragma unroll
      for (int q = 0; q < 4; ++q) row[q] = fp[q * 64 + lane] + sp[q * 64 + lane];
      float bias = fb[(size_t)g * 2048 + p];
#pragma unroll
      for (int j2 = 0; j2 < 8; ++j2)
        if (j2 < nc) {
          float d = 0.f;
#pragma unroll
          for (int q = 0; q < 4; ++q) {
            d = fmaf(row[q][0], latr[j2][q][0], d);
            d = fmaf(row[q][1], latr[j2][q][1], d);
            d = fmaf(row[q][2], latr[j2][q][2], d);
            d = fmaf(row[q][3], latr[j2][q][3], d);
          }
          d += __shfl_xor(d, 32); d += __shfl_xor(d, 16);
          d += __shfl_xor(d, 8);  d += __shfl_xor(d, 4);
          d += __shfl_xor(d, 2);  d += __shfl_xor(d, 1);
          if (lane == 0)
            sb[(size_t)nlist[c0 + j2] * 2048 + p] = f2bf(d + bias);
        }
    }
  }
}

// out(64 x 39548) = sb(64x2048 bf16) @ E(39548x2048 f32)^T + 2*eb
// v12 version: As+Bs LDS dbuf (48KB), BK=64; counted vmcnt(6) + raw barriers.
__global__ __launch_bounds__(256) void gemm_embed(
    const short* __restrict__ sb, const float* __restrict__ E,
    const float* __restrict__ eb, float* __restrict__ out)
{
  __shared__ short As[2 * 64 * 64];   // sb tiles, 16KB
  __shared__ float Bs[2 * 64 * 64];   // E tiles, 32KB
  const int tid  = threadIdx.x;
  const int lane = tid & 63;
  const int wave = tid >> 6;
  const int rl = lane & 15;
  const int lh = lane >> 4;
  const int tile_n = blockIdx.x * 64;       // E-row base

  auto stage = [&](int buf, int k0) {       // 6 gload_lds per thread
#pragma unroll
    for (int c = 0; c < 2; ++c) {
      int o = (c * 256 + tid) * 16;
      int r = o >> 7;
      int cc = ((o >> 4) & 7) ^ (r & 7);
      gload16(sb + (size_t)r * 2048 + k0 + cc * 8,
              (short*)((char*)(As + buf * 4096) + o));
    }
#pragma unroll
    for (int c = 0; c < 4; ++c) {
      int o = (c * 256 + tid) * 16;
      int r = o >> 8;
      int cc = ((o >> 4) & 15) ^ (r & 15);
      int gr = tile_n + r; if (gr > 39547) gr = 39547;   // clamp (masked on write)
      gload16f(E + (size_t)gr * 2048 + k0 + cc * 4,
               (float*)((char*)(Bs + buf * 4096) + o));
    }
  };

  f32x4 acc[4] = {};
  stage(0, 0);                              // 6 outstanding
  int cur = 0;
  for (int t = 0; t < 32; ++t) {
    if (t < 31) {
      stage(cur ^ 1, (t + 1) * 64);         // -> 12
      asm volatile("s_waitcnt vmcnt(6)" ::: "memory");   // stage(t) landed
    } else {
      asm volatile("s_waitcnt vmcnt(0)" ::: "memory");
    }
    __builtin_amdgcn_s_barrier();
    __builtin_amdgcn_sched_barrier(0);
    const char* pa = (const char*)(As + cur * 4096);
    const char* pb = (const char*)(Bs + cur * 4096);
#pragma unroll
    for (int ks = 0; ks < 2; ++ks) {
      int br = wave * 16 + rl;
      int c0 = ks * 8 + lh * 2;
      f32x4 u = *reinterpret_cast<const f32x4*>(pb + br * 256 + ((c0 ^ (br & 15)) * 16));
      f32x4 v = *reinterpret_cast<const f32x4*>(pb + br * 256 + (((c0 + 1) ^ (br & 15)) * 16));
      bf16x8 bf;
      bf[0] = f2bf(u[0]); bf[1] = f2bf(u[1]); bf[2] = f2bf(u[2]); bf[3] = f2bf(u[3]);
      bf[4] = f2bf(v[0]); bf[5] = f2bf(v[1]); bf[6] = f2bf(v[2]); bf[7] = f2bf(v[3]);
#pragma unroll
      for (int mi = 0; mi < 4; ++mi) {
        int ar = mi * 16 + rl;
        int ac = (ks * 4 + lh) ^ (ar & 7);
        bf16x8 af = *reinterpret_cast<const bf16x8*>(pa + ar * 128 + ac * 16);
        acc[mi] = __builtin_amdgcn_mfma_f32_16x16x32_bf16(af, bf, acc[mi], 0, 0, 0);
      }
    }
    __builtin_amdgcn_sched_barrier(0);
    __builtin_amdgcn_s_barrier();
    __builtin_amdgcn_sched_barrier(0);
    cur ^= 1;
  }

  int col = tile_n + wave * 16 + rl;
  if (col < 39548) {
    float bi = 2.f * eb[col];
#pragma unroll
    for (int mi = 0; mi < 4; ++mi)
#pragma unroll
      for (int j = 0; j < 4; ++j) {
        int n = mi * 16 + lh * 4 + j;
        out[(size_t)n * 39548 + col] = acc[mi][j] + bi;
      }
  }
}

extern "C" void kernel_launch(void* const* d_in, const int* in_sizes, int n_in,
                              void* d_out, int out_size, void* d_ws, size_t ws_size,
                              hipStream_t stream)
{
  const float* x0       = (const float*)d_in[0];
  const float* x1       = (const float*)d_in[1];
  const float* w1_0     = (const float*)d_in[2];
  const float* w2_0     = (const float*)d_in[3];
  const float* gamma0   = (const float*)d_in[4];
  const float* beta0    = (const float*)d_in[5];
  const float* w1_1     = (const float*)d_in[6];
  const float* w2_1     = (const float*)d_in[7];
  const float* gamma1   = (const float*)d_in[8];
  const float* beta1    = (const float*)d_in[9];
  const float* shared_w = (const float*)d_in[10];
  const float* fc_w     = (const float*)d_in[11];
  const float* fc_b     = (const float*)d_in[12];
  const float* embed_w  = (const float*)d_in[13];
  const float* embed_b  = (const float*)d_in[14];
  const int*   indices  = (const int*)d_in[15];
  float* out = (float*)d_out;

  // ws layout
  short* x0b  = (short*)d_ws;                       // 16512 x 1024 (64 pad rows)
  short* x1b  = x0b + (size_t)16512 * 1024;         // 12672 x 768  (64 pad rows)
  short* w20b = x1b + (size_t)12672 * 768;          // 1024 x 1024
  short* w21b = w20b + (size_t)1024 * 1024;         // 1024 x 768
  float* w1t0 = (float*)(w21b + (size_t)1024 * 768);// 257 x 1024
  float* w1t1 = w1t0 + (size_t)257 * 1024;          // 197 x 1024
  float* z0   = w1t1 + (size_t)197 * 1024;
  float* z1   = z0 + 64 * 1024;
  float* lat  = z1 + 64 * 1024;
  short* sb   = (short*)(lat + 64 * 1024);          // 64 x 2048 bf16

  // conversions + pads + z zero (13968 blocks) + w1 transposes (288+224 blocks)
  prep<<<14480, 256, 0, stream>>>(x0, x1, w2_0, w2_1, w1_0, w1_1,
                                  x0b, x1b, w20b, w21b, w1t0, w1t1, z0);

  // both feature projections — m97 geometry, fused l-reduction
  gemm_fused_dual<<<1824, 256, 0, stream>>>(x0b, w20b, w1t0, z0,
                                            x1b, w21b, w1t1, z1);

  // BN + latent (row-major)
  bn_latent<<<16, 64, 0, stream>>>(z0, z1, gamma0, beta0, gamma1, beta1, lat);
  // sb = bf16( latent@(shared_w+fc_w_gathered)^T + fc_b ), group-major
  s_combine<<<256, 512, 0, stream>>>(lat, shared_w, fc_w, fc_b, indices, sb);

  // out = sb @ embed_w^T + 2*embed_b, counted-vmcnt dbuf stream, direct write
  gemm_embed<<<618, 256, 0, stream>>>(sb, embed_w, embed_b, out);
}

// Round 14
// 240.946 us; speedup vs baseline: 1.1154x; 1.1154x over previous
//
#include <hip/hip_runtime.h>
#include <hip/hip_bf16.h>

// GroupLinearEncoder: N=64, L0=257,C0=1024, L1=197,C1=768, H=1024, P=2048, G=8, K=39548
// v15 = v12 (best-known, 241.65us) locked in after v11/v13/v14 structural probes
// all regressed:
//   prep: cvt/pad/zero blocks + LDS-tiled 32x32 w1 transpose blocks
//   gemm_fused_dual: 8-wave 256x128, BK=32 dbuf, counted vmcnt(3), setprio MFMA,
//     LDS-staged z epilogue (LDS atomics -> 1 global atomic per (n,col))
//   bn_latent; s_combine (group-major, ballot nlist)
//   gemm_embed: As+Bs LDS dbuf (48KB), BK=64, raw-f32 E staging via global_load_lds,
//     counted vmcnt(6) + raw barriers, direct out write + 2*embed_b

typedef __attribute__((ext_vector_type(4))) float f32x4;
typedef __attribute__((ext_vector_type(8))) short bf16x8;

__device__ __forceinline__ short f2bf(float v) {
  __hip_bfloat16 h = __float2bfloat16(v);
  union { __hip_bfloat16 b; short s; } u; u.b = h; return u.s;
}

__device__ __forceinline__ void gload16(const short* g, short* l) {
  __builtin_amdgcn_global_load_lds(
      (const __attribute__((address_space(1))) void*)g,
      (__attribute__((address_space(3))) void*)l, 16, 0, 0);
}

__device__ __forceinline__ void gload16f(const float* g, float* l) {
  __builtin_amdgcn_global_load_lds(
      (const __attribute__((address_space(1))) void*)g,
      (__attribute__((address_space(3))) void*)l, 16, 0, 0);
}

__device__ __forceinline__ void cvt8(const float* __restrict__ in,
                                     short* __restrict__ out, size_t i) {
  const float4* p = reinterpret_cast<const float4*>(in) + 2 * i;
  float4 a = p[0], b = p[1];
  bf16x8 o;
  o[0] = f2bf(a.x); o[1] = f2bf(a.y); o[2] = f2bf(a.z); o[3] = f2bf(a.w);
  o[4] = f2bf(b.x); o[5] = f2bf(b.y); o[6] = f2bf(b.z); o[7] = f2bf(b.w);
  *reinterpret_cast<bf16x8*>(out + 8 * i) = o;
}

// blocks [0,13968): elementwise cvt/pad/zero; [13968,14480): tiled w1 transpose.
__global__ __launch_bounds__(256) void prep(
    const float* __restrict__ x0, const float* __restrict__ x1,
    const float* __restrict__ w20, const float* __restrict__ w21,
    const float* __restrict__ w10, const float* __restrict__ w11,
    short* __restrict__ x0b, short* __restrict__ x1b,
    short* __restrict__ w20b, short* __restrict__ w21b,
    float* __restrict__ w1t0, float* __restrict__ w1t1,
    float* __restrict__ zz)
{
  __shared__ float tile[32][33];
  if (blockIdx.x >= 13968) {
    // coalesced 32x32 LDS transpose: w1t[l*1024+k] = w1[k*L+l]
    int b = blockIdx.x - 13968;
    const float* src; float* dst; int Lw;
    if (b < 288) { src = w10; dst = w1t0; Lw = 257; }
    else         { b -= 288; src = w11; dst = w1t1; Lw = 197; }
    int kt = b & 31, lt = b >> 5;
    int c = threadIdx.x & 31, r8 = threadIdx.x >> 5;
#pragma unroll
    for (int i = 0; i < 4; ++i) {
      int a = r8 + 8 * i;                // k-local
      int l = lt * 32 + c;
      tile[a][c] = (l < Lw) ? src[(size_t)(kt * 32 + a) * Lw + l] : 0.f;
    }
    __syncthreads();
#pragma unroll
    for (int i = 0; i < 4; ++i) {
      int bl = r8 + 8 * i;               // l-local
      int l = lt * 32 + bl;
      if (l < Lw) dst[(size_t)l * 1024 + kt * 32 + c] = tile[c][bl];
    }
    return;
  }
  size_t i = (size_t)blockIdx.x * 256 + threadIdx.x;
  const size_t C0 = 2105344;            // x0 cvt  (16448*1024/8)
  const size_t C1 = C0 + 8192;          // x0 pad
  const size_t C2 = C1 + 1210368;       // x1 cvt  (12608*768/8)
  const size_t C3 = C2 + 6144;          // x1 pad
  const size_t C4 = C3 + 131072;        // w2_0
  const size_t C5 = C4 + 98304;         // w2_1
  // C5 + 16384 (z zero) = 3575808 = 256*13968
  if (i < C0) { cvt8(x0, x0b, i); return; }
  if (i < C1) {
    bf16x8 zv = {};
    *reinterpret_cast<bf16x8*>(x0b + (size_t)16448 * 1024 + 8 * (i - C0)) = zv;
    return;
  }
  if (i < C2) { cvt8(x1, x1b, i - C1); return; }
  if (i < C3) {
    bf16x8 zv = {};
    *reinterpret_cast<bf16x8*>(x1b + (size_t)12608 * 768 + 8 * (i - C2)) = zv;
    return;
  }
  if (i < C4) { cvt8(w20, w20b, i - C3); return; }
  if (i < C5) { cvt8(w21, w21b, i - C4); return; }
  f32x4 z4 = {};
  f32x4* zp = reinterpret_cast<f32x4*>(zz) + 2 * (i - C5);
  zp[0] = z4; zp[1] = z4;
}

// ---- fused feature-projection GEMM body (8 waves, 256x128 tile, BK=32 dbuf) ----
template<int L>
__device__ __forceinline__ void fused_body(
    const short* __restrict__ Ab, const short* __restrict__ Bb,
    const float* __restrict__ w1t, float* __restrict__ z,
    int Mpad, int M, int K, int orig, short* As, short* Bs, float* zacc, int tid)
{
  const int lane = tid & 63;
  const int wave = tid >> 6;             // 0..7
  const int wm = wave >> 1, wn = wave & 1;
  const int tile_m = (orig >> 3) * 256;
  const int tile_n = (orig & 7) * 128;
  const int rl = lane & 15;
  const int lh = lane >> 4;

  zacc[tid] = 0.f;

  f32x4 acc[4][4] = {};
  const int nt = K >> 5;

  auto stage = [&](short* dA, short* dB, int k0) {   // 3 gload_lds per thread
#pragma unroll
    for (int c = 0; c < 2; ++c) {
      int o = (c * 512 + tid) * 16;
      int r = o >> 6;
      int sc = ((o >> 4) & 3) ^ ((r >> 1) & 3);
      int gr = tile_m + r; if (gr >= Mpad) gr = Mpad - 1;
      gload16(Ab + (size_t)gr * K + k0 + sc * 8, (short*)((char*)dA + o));
    }
    {
      int o = tid * 16;
      int r = o >> 6;
      int sc = ((o >> 4) & 3) ^ ((r >> 1) & 3);
      gload16(Bb + (size_t)(tile_n + r) * K + k0 + sc * 8, (short*)((char*)dB + o));
    }
  };

  stage(As, Bs, 0);
  int cur = 0;
  for (int t = 0; t < nt; ++t) {
    if (t + 1 < nt) {
      stage(As + (cur ^ 1) * 8192, Bs + (cur ^ 1) * 4096, (t + 1) * 32);
      asm volatile("s_waitcnt vmcnt(3)" ::: "memory");
    } else {
      asm volatile("s_waitcnt vmcnt(0)" ::: "memory");
    }
    __builtin_amdgcn_s_barrier();
    __builtin_amdgcn_sched_barrier(0);
    const char* pa = (const char*)(As + cur * 8192);
    const char* pb = (const char*)(Bs + cur * 4096);
    bf16x8 af[4], bfr[4];
#pragma unroll
    for (int mi = 0; mi < 4; ++mi) {
      int r = wm * 64 + mi * 16 + rl;
      int j = lh ^ ((r >> 1) & 3);
      af[mi] = *reinterpret_cast<const bf16x8*>(pa + r * 64 + j * 16);
    }
#pragma unroll
    for (int ni = 0; ni < 4; ++ni) {
      int r = wn * 64 + ni * 16 + rl;
      int j = lh ^ ((r >> 1) & 3);
      bfr[ni] = *reinterpret_cast<const bf16x8*>(pb + r * 64 + j * 16);
    }
    __builtin_amdgcn_s_setprio(1);
#pragma unroll
    for (int mi = 0; mi < 4; ++mi)
#pragma unroll
      for (int ni = 0; ni < 4; ++ni)
        acc[mi][ni] = __builtin_amdgcn_mfma_f32_16x16x32_bf16(af[mi], bfr[ni], acc[mi][ni], 0, 0, 0);
    __builtin_amdgcn_s_setprio(0);
    __builtin_amdgcn_sched_barrier(0);
    __builtin_amdgcn_s_barrier();
    __builtin_amdgcn_sched_barrier(0);
    cur ^= 1;
  }

  // epilogue: partials -> LDS zacc via LDS atomics, then one global atomic each.
  const int nbase = tile_m / L;
#pragma unroll
  for (int ni = 0; ni < 4; ++ni) {
    int colL = wn * 64 + ni * 16 + rl;
    int col = tile_n + colL;
    float zac = 0.f;
    int curdn = -1;
#pragma unroll
    for (int mi = 0; mi < 4; ++mi) {
#pragma unroll
      for (int j = 0; j < 4; ++j) {
        int row = tile_m + wm * 64 + mi * 16 + lh * 4 + j;
        if (row < M) {
          int n = row / L, l = row - n * L;
          float v = acc[mi][ni][j] * w1t[(size_t)l * 1024 + col];
          int dn = n - nbase;
          if (dn != curdn) {
            if (curdn >= 0) atomicAdd(&zacc[curdn * 128 + colL], zac);
            curdn = dn; zac = 0.f;
          }
          zac += v;
        }
      }
    }
    if (curdn >= 0) atomicAdd(&zacc[curdn * 128 + colL], zac);
  }
  __syncthreads();
  {
    int dn = tid >> 7, c = tid & 127;
    int mtop = tile_m + 255; if (mtop > M - 1) mtop = M - 1;
    int nhi = mtop / L;
    int n = nbase + dn;
    if (n <= nhi)
      atomicAdd(z + (size_t)n * 1024 + tile_n + c, zacc[tid]);
  }
}

// blocks [0,520) path0 (65x8 tiles), [520,920) path1 (50x8). XCD-chunked swizzle.
__global__ __launch_bounds__(512) void gemm_fused_dual(
    const short* __restrict__ x0b, const short* __restrict__ w20b,
    const float* __restrict__ w1t0, float* __restrict__ z0,
    const short* __restrict__ x1b, const short* __restrict__ w21b,
    const float* __restrict__ w1t1, float* __restrict__ z1)
{
  __shared__ short As[2 * 8192];   // 32KB
  __shared__ short Bs[2 * 4096];   // 16KB
  __shared__ float zacc[512];      // 2KB
  const int flat = blockIdx.x;
  const int tid = threadIdx.x;
  if (flat < 520) {
    const int orig = (flat & 7) * 65 + (flat >> 3);
    fused_body<257>(x0b, w20b, w1t0, z0, 16512, 16448, 1024, orig, As, Bs, zacc, tid);
  } else {
    const int f = flat - 520;
    const int orig = (f & 7) * 50 + (f >> 3);
    fused_body<197>(x1b, w21b, w1t1, z1, 12672, 12608, 768, orig, As, Bs, zacc, tid);
  }
}

// BN(z0), BN(z1) (biased stats over n=64), latent=0.5*(...+...), stored lat[n*1024+k]
__global__ void bn_latent(const float* __restrict__ z0, const float* __restrict__ z1,
                          const float* __restrict__ g0, const float* __restrict__ b0,
                          const float* __restrict__ g1, const float* __restrict__ b1,
                          float* __restrict__ lat)
{
  int k = blockIdx.x * blockDim.x + threadIdx.x;
  if (k >= 1024) return;
  float s0 = 0.f, q0 = 0.f, s1 = 0.f, q1 = 0.f;
  for (int n = 0; n < 64; ++n) {
    float v = z0[n * 1024 + k]; s0 += v; q0 += v * v;
    float w = z1[n * 1024 + k]; s1 += w; q1 += w * w;
  }
  float mu0 = s0 * (1.f / 64.f), var0 = q0 * (1.f / 64.f) - mu0 * mu0;
  float mu1 = s1 * (1.f / 64.f), var1 = q1 * (1.f / 64.f) - mu1 * mu1;
  float sc0 = g0[k] * rsqrtf(var0 + 1e-5f);
  float sc1 = g1[k] * rsqrtf(var1 + 1e-5f);
  float be0 = b0[k], be1 = b1[k];
  for (int n = 0; n < 64; ++n) {
    float v = sc0 * (z0[n * 1024 + k] - mu0) + be0
            + sc1 * (z1[n * 1024 + k] - mu1) + be1;
    lat[n * 1024 + k] = 0.5f * v;
  }
}

// sb[n,p] = bf16( lat[n,:]·(sw[p,:]+fw[g_n*2048+p,:]) + fb[g_n*2048+p] )
__global__ __launch_bounds__(512) void s_combine(
    const float* __restrict__ lat, const float* __restrict__ sw,
    const float* __restrict__ fw, const float* __restrict__ fb,
    const int* __restrict__ idx, short* __restrict__ sb)
{
  __shared__ int nlist[64];
  __shared__ int ncnt;
  const int g  = blockIdx.x >> 5;
  const int pc = blockIdx.x & 31;
  const int tid = threadIdx.x;
  const int lane = tid & 63;
  const int wave = tid >> 6;

  if (wave == 0) {
    int match = (idx[lane] == g) ? 1 : 0;
    unsigned long long m = __ballot(match);
    if (match) {
      int pos = __popcll(m & ((1ull << lane) - 1ull));
      nlist[pos] = lane;
    }
    if (lane == 0) ncnt = __popcll(m);
  }
  __syncthreads();
  const int cnt = ncnt;
  if (cnt == 0) return;

  for (int c0 = 0; c0 < cnt; c0 += 8) {
    const int nc = (cnt - c0 < 8) ? (cnt - c0) : 8;
    f32x4 latr[8][4];
#pragma unroll
    for (int j2 = 0; j2 < 8; ++j2)
      if (j2 < nc) {
        const f32x4* lp = reinterpret_cast<const f32x4*>(lat + (size_t)nlist[c0 + j2] * 1024);
#pragma unroll
        for (int q = 0; q < 4; ++q) latr[j2][q] = lp[q * 64 + lane];
      }
#pragma unroll 2
    for (int pi = 0; pi < 8; ++pi) {
      int p = pc * 64 + wave * 8 + pi;
      const f32x4* fp = reinterpret_cast<const f32x4*>(fw + ((size_t)g * 2048 + p) * 1024);
      const f32x4* sp = reinterpret_cast<const f32x4*>(sw + (size_t)p * 1024);
      f32x4 row[4];
#pragma unroll
      for (int q = 0; q < 4; ++q) row[q] = fp[q * 64 + lane] + sp[q * 64 + lane];
      float bias = fb[(size_t)g * 2048 + p];
#pragma unroll
      for (int j2 = 0; j2 < 8; ++j2)
        if (j2 < nc) {
          float d = 0.f;
#pragma unroll
          for (int q = 0; q < 4; ++q) {
            d = fmaf(row[q][0], latr[j2][q][0], d);
            d = fmaf(row[q][1], latr[j2][q][1], d);
            d = fmaf(row[q][2], latr[j2][q][2], d);
            d = fmaf(row[q][3], latr[j2][q][3], d);
          }
          d += __shfl_xor(d, 32); d += __shfl_xor(d, 16);
          d += __shfl_xor(d, 8);  d += __shfl_xor(d, 4);
          d += __shfl_xor(d, 2);  d += __shfl_xor(d, 1);
          if (lane == 0)
            sb[(size_t)nlist[c0 + j2] * 2048 + p] = f2bf(d + bias);
        }
    }
  }
}

// out(64 x 39548) = sb(64x2048 bf16) @ E(39548x2048 f32)^T + 2*eb
// As+Bs LDS dbuf (48KB), BK=64; counted vmcnt(6) + raw barriers.
__global__ __launch_bounds__(256) void gemm_embed(
    const short* __restrict__ sb, const float* __restrict__ E,
    const float* __restrict__ eb, float* __restrict__ out)
{
  __shared__ short As[2 * 64 * 64];   // sb tiles, 16KB
  __shared__ float Bs[2 * 64 * 64];   // E tiles, 32KB
  const int tid  = threadIdx.x;
  const int lane = tid & 63;
  const int wave = tid >> 6;
  const int rl = lane & 15;
  const int lh = lane >> 4;
  const int tile_n = blockIdx.x * 64;       // E-row base

  auto stage = [&](int buf, int k0) {       // 6 gload_lds per thread
#pragma unroll
    for (int c = 0; c < 2; ++c) {
      int o = (c * 256 + tid) * 16;
      int r = o >> 7;
      int cc = ((o >> 4) & 7) ^ (r & 7);
      gload16(sb + (size_t)r * 2048 + k0 + cc * 8,
              (short*)((char*)(As + buf * 4096) + o));
    }
#pragma unroll
    for (int c = 0; c < 4; ++c) {
      int o = (c * 256 + tid) * 16;
      int r = o >> 8;
      int cc = ((o >> 4) & 15) ^ (r & 15);
      int gr = tile_n + r; if (gr > 39547) gr = 39547;   // clamp (masked on write)
      gload16f(E + (size_t)gr * 2048 + k0 + cc * 4,
               (float*)((char*)(Bs + buf * 4096) + o));
    }
  };

  f32x4 acc[4] = {};
  stage(0, 0);                              // 6 outstanding
  int cur = 0;
  for (int t = 0; t < 32; ++t) {
    if (t < 31) {
      stage(cur ^ 1, (t + 1) * 64);         // -> 12
      asm volatile("s_waitcnt vmcnt(6)" ::: "memory");   // stage(t) landed
    } else {
      asm volatile("s_waitcnt vmcnt(0)" ::: "memory");
    }
    __builtin_amdgcn_s_barrier();
    __builtin_amdgcn_sched_barrier(0);
    const char* pa = (const char*)(As + cur * 4096);
    const char* pb = (const char*)(Bs + cur * 4096);
#pragma unroll
    for (int ks = 0; ks < 2; ++ks) {
      int br = wave * 16 + rl;
      int c0 = ks * 8 + lh * 2;
      f32x4 u = *reinterpret_cast<const f32x4*>(pb + br * 256 + ((c0 ^ (br & 15)) * 16));
      f32x4 v = *reinterpret_cast<const f32x4*>(pb + br * 256 + (((c0 + 1) ^ (br & 15)) * 16));
      bf16x8 bf;
      bf[0] = f2bf(u[0]); bf[1] = f2bf(u[1]); bf[2] = f2bf(u[2]); bf[3] = f2bf(u[3]);
      bf[4] = f2bf(v[0]); bf[5] = f2bf(v[1]); bf[6] = f2bf(v[2]); bf[7] = f2bf(v[3]);
#pragma unroll
      for (int mi = 0; mi < 4; ++mi) {
        int ar = mi * 16 + rl;
        int ac = (ks * 4 + lh) ^ (ar & 7);
        bf16x8 af = *reinterpret_cast<const bf16x8*>(pa + ar * 128 + ac * 16);
        acc[mi] = __builtin_amdgcn_mfma_f32_16x16x32_bf16(af, bf, acc[mi], 0, 0, 0);
      }
    }
    __builtin_amdgcn_sched_barrier(0);
    __builtin_amdgcn_s_barrier();
    __builtin_amdgcn_sched_barrier(0);
    cur ^= 1;
  }

  int col = tile_n + wave * 16 + rl;
  if (col < 39548) {
    float bi = 2.f * eb[col];
#pragma unroll
    for (int mi = 0; mi < 4; ++mi)
#pragma unroll
      for (int j = 0; j < 4; ++j) {
        int n = mi * 16 + lh * 4 + j;
        out[(size_t)n * 39548 + col] = acc[mi][j] + bi;
      }
  }
}

extern "C" void kernel_launch(void* const* d_in, const int* in_sizes, int n_in,
                              void* d_out, int out_size, void* d_ws, size_t ws_size,
                              hipStream_t stream)
{
  const float* x0       = (const float*)d_in[0];
  const float* x1       = (const float*)d_in[1];
  const float* w1_0     = (const float*)d_in[2];
  const float* w2_0     = (const float*)d_in[3];
  const float* gamma0   = (const float*)d_in[4];
  const float* beta0    = (const float*)d_in[5];
  const float* w1_1     = (const float*)d_in[6];
  const float* w2_1     = (const float*)d_in[7];
  const float* gamma1   = (const float*)d_in[8];
  const float* beta1    = (const float*)d_in[9];
  const float* shared_w = (const float*)d_in[10];
  const float* fc_w     = (const float*)d_in[11];
  const float* fc_b     = (const float*)d_in[12];
  const float* embed_w  = (const float*)d_in[13];
  const float* embed_b  = (const float*)d_in[14];
  const int*   indices  = (const int*)d_in[15];
  float* out = (float*)d_out;

  // ws layout
  short* x0b  = (short*)d_ws;                       // 16512 x 1024 (64 pad rows)
  short* x1b  = x0b + (size_t)16512 * 1024;         // 12672 x 768  (64 pad rows)
  short* w20b = x1b + (size_t)12672 * 768;          // 1024 x 1024
  short* w21b = w20b + (size_t)1024 * 1024;         // 1024 x 768
  float* w1t0 = (float*)(w21b + (size_t)1024 * 768);// 257 x 1024
  float* w1t1 = w1t0 + (size_t)257 * 1024;          // 197 x 1024
  float* z0   = w1t1 + (size_t)197 * 1024;
  float* z1   = z0 + 64 * 1024;
  float* lat  = z1 + 64 * 1024;
  short* sb   = (short*)(lat + 64 * 1024);          // 64 x 2048 bf16

  // conversions + pads + z zero (13968 blocks) + w1 transposes (288+224 blocks)
  prep<<<14480, 256, 0, stream>>>(x0, x1, w2_0, w2_1, w1_0, w1_1,
                                  x0b, x1b, w20b, w21b, w1t0, w1t1, z0);

  // both feature projections (fused l-reduction, LDS-staged z epilogue)
  gemm_fused_dual<<<920, 512, 0, stream>>>(x0b, w20b, w1t0, z0,
                                           x1b, w21b, w1t1, z1);

  // BN + latent (row-major)
  bn_latent<<<16, 64, 0, stream>>>(z0, z1, gamma0, beta0, gamma1, beta1, lat);
  // sb = bf16( latent@(shared_w+fc_w_gathered)^T + fc_b ), group-major
  s_combine<<<256, 512, 0, stream>>>(lat, shared_w, fc_w, fc_b, indices, sb);

  // out = sb @ embed_w^T + 2*embed_b, counted-vmcnt dbuf stream, direct write
  gemm_embed<<<618, 256, 0, stream>>>(sb, embed_w, embed_b, out);
}